// Round 3
// baseline (5810.951 us; speedup 1.0000x reference)
//
#include <hip/hip_runtime.h>
#include <hip/hip_fp16.h>

// Problem constants
#define TT 2048
#define II 1739
#define HN 256
#define H3 768

typedef _Float16 h2 __attribute__((ext_vector_type(2)));

__device__ __forceinline__ float fdot2(h2 a, h2 b, float c) {
#if defined(__has_builtin)
#if __has_builtin(__builtin_amdgcn_fdot2)
  return __builtin_amdgcn_fdot2(a, b, c, false);
#else
  return fmaf((float)a[0], (float)b[0], fmaf((float)a[1], (float)b[1], c));
#endif
#else
  return fmaf((float)a[0], (float)b[0], fmaf((float)a[1], (float)b[1], c));
#endif
}

template <int CTRL>
__device__ __forceinline__ float dpp_qperm(float v) {
  int r = __builtin_amdgcn_update_dpp(0, __builtin_bit_cast(int, v), CTRL, 0xF, 0xF, true);
  return __builtin_bit_cast(float, r);
}

// C[M,N] = A[M,K] @ B[N,K]^T + bias1[n] + (n < b2lim ? bias2[n] : 0)
// 64x64 tile, 256 threads, 4x4 micro-tile per thread.
__global__ __launch_bounds__(256) void gemm_abt(
    const float* __restrict__ A, int M, int K,
    const float* __restrict__ B, int N,
    const float* __restrict__ bias1, const float* __restrict__ bias2, int b2lim,
    float* __restrict__ C) {
  __shared__ float As[16][64];
  __shared__ float Bs[16][64];
  const int tid = threadIdx.x;
  const int m0 = blockIdx.y * 64, n0 = blockIdx.x * 64;
  const int lr = tid >> 2;        // 0..63  (row within tile for loads)
  const int lk = (tid & 3) * 4;   // 0,4,8,12
  const int cx = tid & 15, cy = tid >> 4;
  float acc[4][4] = {};

  for (int k0 = 0; k0 < K; k0 += 16) {
#pragma unroll
    for (int i = 0; i < 4; ++i) {
      int k = k0 + lk + i;
      As[lk + i][lr] = (k < K) ? A[(size_t)(m0 + lr) * K + k] : 0.f;
      int bn = n0 + lr;
      Bs[lk + i][lr] = (k < K && bn < N) ? B[(size_t)bn * K + k] : 0.f;
    }
    __syncthreads();
#pragma unroll
    for (int k = 0; k < 16; ++k) {
      float4 av = *(const float4*)&As[k][cy * 4];
      float4 bv = *(const float4*)&Bs[k][cx * 4];
      const float aa[4] = {av.x, av.y, av.z, av.w};
      const float bb[4] = {bv.x, bv.y, bv.z, bv.w};
#pragma unroll
      for (int i = 0; i < 4; ++i)
#pragma unroll
        for (int j = 0; j < 4; ++j) acc[i][j] = fmaf(aa[i], bb[j], acc[i][j]);
    }
    __syncthreads();
  }
#pragma unroll
  for (int i = 0; i < 4; ++i) {
    int m = m0 + cy * 4 + i;
#pragma unroll
    for (int j = 0; j < 4; ++j) {
      int n = n0 + cx * 4 + j;
      if (n < N) {
        float b = bias1 ? bias1[n] : 0.f;
        if (bias2 && n < b2lim) b += bias2[n];
        C[(size_t)m * N + n] = acc[i][j] + b;
      }
    }
  }
}

// Sequential GRU scan on a single CU (1 block, 1024 threads = 16 waves).
//
// Round 1-2 finding: the compiler pins this kernel at 128 arch VGPRs no
// matter what occupancy attributes we pass; a 192-dword weight array then
// pays a per-fdot2 accvgpr/copy tax. Fix by CONSTRUCTION: 1024 threads,
// 3 rows x 64 k per thread -> wreg[3][32] = 96 dwords + chunked uint4
// staging (4 dwords live) -> ~115 live regs < 128 cap. No copy tax
// possible, and 4 waves/SIMD hide LDS/DPP latency better than 2.
//
// Thread layout: wave wv (0..15), lane; kc = lane&3 -> k-chunk [64*kc, +64)
// row-group g = wv*16 + (lane>>2) in [0,256), rows r = 3g..3g+2.
// xp = x @ W_ih^T + b_ih + (b_hh for r,z rows only). b_hh n-part in-gate.
//
// hbuf layout: h (256 f16 = 128 dwords) split into 4 k-chunks of 32 dwords,
// chunk kc at dword offset kc*40 (8-dword pad) -> the four distinct
// per-quad b128 addresses hit disjoint banks (conflict counter verified 0;
// 16 same-kc lanes/wave read the same address -> broadcast, free).
__global__ __launch_bounds__(1024) void gru_seq(
    const float* __restrict__ xp,      // [T, 768]
    const float* __restrict__ Whh,     // [768, 256]
    const float* __restrict__ bhh,     // [768]
    const float* __restrict__ h0,      // [256] or nullptr (zeros)
    float* __restrict__ hs_out,        // [T, 256] or nullptr
    float* __restrict__ hT_out) {      // [256] or nullptr
  __shared__ __align__(16) uint hbufd[4 * 40];  // 4 chunks, 40-dword stride
  __shared__ float hh[H3];

  const int tid = threadIdx.x;
  const int lane = tid & 63;
  const int wv = tid >> 6;               // 0..15
  const int kc = lane & 3;
  const int g = wv * 16 + (lane >> 2);   // 0..255
  const int r0 = g * 3;                  // 0..765

  // Load W_hh rows into registers as packed f16 pairs (96 dwords).
  h2 wreg[3][32];
#pragma unroll
  for (int i = 0; i < 3; ++i) {
    const float* wr = Whh + (size_t)(r0 + i) * HN + kc * 64;
#pragma unroll
    for (int p = 0; p < 32; ++p) {
      float2 f = *(const float2*)(wr + 2 * p);
      wreg[i][p] = h2{(_Float16)f.x, (_Float16)f.y};
    }
  }

  float hj = 0.f, bhn = 0.f;
  if (tid < HN) {
    hj = h0 ? h0[tid] : 0.f;
    bhn = bhh[2 * HN + tid];
  }
  if (tid < 128) {
    float a = h0 ? h0[2 * tid] : 0.f;
    float b = h0 ? h0[2 * tid + 1] : 0.f;
    h2 pv = h2{(_Float16)a, (_Float16)b};
    hbufd[(tid >> 5) * 40 + (tid & 31)] = __builtin_bit_cast(uint, pv);
  }
  __syncthreads();

  const uint* hb = &hbufd[kc * 40];

  for (int t = 0; t < TT; ++t) {
    // Prefetch this step's x-projection (lands during the matvec).
    float xr = 0.f, xz = 0.f, xn = 0.f;
    if (tid < HN) {
      const float* xpt = xp + (size_t)t * H3 + tid;
      xr = xpt[0];
      xz = xpt[HN];
      xn = xpt[2 * HN];
    }

    // Matvec: 3 rows x 64 k per thread, f16 dot2 with fp32 accumulate.
    // Chunked staging: one uint4 of h live at a time (4 pairs -> 4 fdot2/row).
    float acc[3] = {0.f, 0.f, 0.f};
#pragma unroll
    for (int q = 0; q < 8; ++q) {
      uint4 v = *(const uint4*)&hb[q * 4];
      h2 p0 = __builtin_bit_cast(h2, v.x);
      h2 p1 = __builtin_bit_cast(h2, v.y);
      h2 p2 = __builtin_bit_cast(h2, v.z);
      h2 p3 = __builtin_bit_cast(h2, v.w);
#pragma unroll
      for (int i = 0; i < 3; ++i) {
        acc[i] = fdot2(wreg[i][q * 4 + 0], p0, acc[i]);
        acc[i] = fdot2(wreg[i][q * 4 + 1], p1, acc[i]);
        acc[i] = fdot2(wreg[i][q * 4 + 2], p2, acc[i]);
        acc[i] = fdot2(wreg[i][q * 4 + 3], p3, acc[i]);
      }
    }

    // Reduce the 4 k-chunk partials within each quad (pure VALU via DPP).
#pragma unroll
    for (int i = 0; i < 3; ++i) {
      float v = acc[i];
      v += dpp_qperm<0xB1>(v);  // xor 1
      v += dpp_qperm<0x4E>(v);  // xor 2
      acc[i] = v;
    }
    if (kc == 0) {
      // 16 active lanes/wave, dword stride 3 -> all banks distinct.
      hh[r0 + 0] = acc[0];
      hh[r0 + 1] = acc[1];
      hh[r0 + 2] = acc[2];
    }
    __syncthreads();

    // Gates (threads 0..255, one per hidden unit).
    if (tid < HN) {
      float r = 1.f / (1.f + __expf(-(xr + hh[tid])));
      float z = 1.f / (1.f + __expf(-(xz + hh[HN + tid])));
      float nv = 2.f / (1.f + __expf(-2.f * (xn + r * (hh[2 * HN + tid] + bhn)))) - 1.f;
      hj = (1.f - z) * nv + z * hj;
      if (hs_out) hs_out[(size_t)t * HN + tid] = hj;
      ((_Float16*)&hbufd[(tid >> 6) * 40 + ((tid >> 1) & 31)])[tid & 1] = (_Float16)hj;
    }
    __syncthreads();
  }
  if (hT_out && tid < HN) hT_out[tid] = hj;
}

extern "C" void kernel_launch(void* const* d_in, const int* in_sizes, int n_in,
                              void* d_out, int out_size, void* d_ws, size_t ws_size,
                              hipStream_t stream) {
  const float* x     = (const float*)d_in[0];   // [1, 2048, 1739]
  const float* Wih_e = (const float*)d_in[2];   // [768, 1739]
  const float* Whh_e = (const float*)d_in[3];   // [768, 256]
  const float* bih_e = (const float*)d_in[4];   // [768]
  const float* bhh_e = (const float*)d_in[5];   // [768]
  const float* Wih_d = (const float*)d_in[6];
  const float* Whh_d = (const float*)d_in[7];
  const float* bih_d = (const float*)d_in[8];
  const float* bhh_d = (const float*)d_in[9];
  const float* Wout  = (const float*)d_in[10];  // [1739, 256]
  const float* bout  = (const float*)d_in[11];  // [1739]
  float* out = (float*)d_out;                   // [2048, 1, 1739]

  float* ws = (float*)d_ws;
  float* xpe  = ws;                              // 2048*768
  float* xpd  = xpe + (size_t)TT * H3;           // 2048*768
  float* hs   = xpd + (size_t)TT * H3;           // 2048*256
  float* henc = hs + (size_t)TT * HN;            // 256

  dim3 blk(256);
  // x-projections (b_hh folded in for r,z rows; n rows get b_ih only)
  gemm_abt<<<dim3(12, 32), blk, 0, stream>>>(x, TT, II, Wih_e, H3, bih_e, bhh_e, 2 * HN, xpe);
  gemm_abt<<<dim3(12, 32), blk, 0, stream>>>(x, TT, II, Wih_d, H3, bih_d, bhh_d, 2 * HN, xpd);
  // encoder scan -> henc
  gru_seq<<<1, 1024, 0, stream>>>(xpe, Whh_e, bhh_e, nullptr, nullptr, henc);
  // decoder scan -> hs
  gru_seq<<<1, 1024, 0, stream>>>(xpd, Whh_d, bhh_d, henc, hs, nullptr);
  // output projection
  gemm_abt<<<dim3(28, 32), blk, 0, stream>>>(hs, TT, HN, Wout, II, bout, nullptr, 0, out);
}

// Round 4
// 5025.629 us; speedup vs baseline: 1.1563x; 1.1563x over previous
//
#include <hip/hip_runtime.h>
#include <hip/hip_fp16.h>

// Problem constants
#define TT 2048
#define II 1739
#define HN 256
#define H3 768
#define L2E 1.44269504088896f

typedef _Float16 h2 __attribute__((ext_vector_type(2)));

__device__ __forceinline__ float fdot2(h2 a, h2 b, float c) {
#if defined(__has_builtin)
#if __has_builtin(__builtin_amdgcn_fdot2)
  return __builtin_amdgcn_fdot2(a, b, c, false);
#else
  return fmaf((float)a[0], (float)b[0], fmaf((float)a[1], (float)b[1], c));
#endif
#else
  return fmaf((float)a[0], (float)b[0], fmaf((float)a[1], (float)b[1], c));
#endif
}

__device__ __forceinline__ float fast_exp2(float x) {
#if defined(__has_builtin)
#if __has_builtin(__builtin_amdgcn_exp2f)
  return __builtin_amdgcn_exp2f(x);
#else
  return exp2f(x);
#endif
#else
  return exp2f(x);
#endif
}

__device__ __forceinline__ float fast_rcp(float x) {
#if defined(__has_builtin)
#if __has_builtin(__builtin_amdgcn_rcpf)
  return __builtin_amdgcn_rcpf(x);
#else
  return 1.f / x;
#endif
#else
  return 1.f / x;
#endif
}

template <int CTRL>
__device__ __forceinline__ float dpp_qperm(float v) {
  int r = __builtin_amdgcn_update_dpp(0, __builtin_bit_cast(int, v), CTRL, 0xF, 0xF, true);
  return __builtin_bit_cast(float, r);
}

// C[M,N] = ((A[M,K] @ B[N,K]^T) + bias1[n] + (n < b2lim ? bias2[n] : 0)) * (n < slim ? s_lo : s_hi)
// 64x64 tile, 256 threads, 4x4 micro-tile per thread.
__global__ __launch_bounds__(256) void gemm_abt(
    const float* __restrict__ A, int M, int K,
    const float* __restrict__ B, int N,
    const float* __restrict__ bias1, const float* __restrict__ bias2, int b2lim,
    float s_lo, float s_hi, int slim,
    float* __restrict__ C) {
  __shared__ float As[16][64];
  __shared__ float Bs[16][64];
  const int tid = threadIdx.x;
  const int m0 = blockIdx.y * 64, n0 = blockIdx.x * 64;
  const int lr = tid >> 2;        // 0..63  (row within tile for loads)
  const int lk = (tid & 3) * 4;   // 0,4,8,12
  const int cx = tid & 15, cy = tid >> 4;
  float acc[4][4] = {};

  for (int k0 = 0; k0 < K; k0 += 16) {
#pragma unroll
    for (int i = 0; i < 4; ++i) {
      int k = k0 + lk + i;
      As[lk + i][lr] = (k < K) ? A[(size_t)(m0 + lr) * K + k] : 0.f;
      int bn = n0 + lr;
      Bs[lk + i][lr] = (k < K && bn < N) ? B[(size_t)bn * K + k] : 0.f;
    }
    __syncthreads();
#pragma unroll
    for (int k = 0; k < 16; ++k) {
      float4 av = *(const float4*)&As[k][cy * 4];
      float4 bv = *(const float4*)&Bs[k][cx * 4];
      const float aa[4] = {av.x, av.y, av.z, av.w};
      const float bb[4] = {bv.x, bv.y, bv.z, bv.w};
#pragma unroll
      for (int i = 0; i < 4; ++i)
#pragma unroll
        for (int j = 0; j < 4; ++j) acc[i][j] = fmaf(aa[i], bb[j], acc[i][j]);
    }
    __syncthreads();
  }
#pragma unroll
  for (int i = 0; i < 4; ++i) {
    int m = m0 + cy * 4 + i;
#pragma unroll
    for (int j = 0; j < 4; ++j) {
      int n = n0 + cx * 4 + j;
      if (n < N) {
        float b = bias1 ? bias1[n] : 0.f;
        if (bias2 && n < b2lim) b += bias2[n];
        float s = (n < slim) ? s_lo : s_hi;
        C[(size_t)m * N + n] = (acc[i][j] + b) * s;
      }
    }
  }
}

// Sequential GRU scan on a single CU (1 block, 512 threads = 8 waves).
//
// Rounds 0-3 established: register residency of wreg does NOT matter
// (64/128-VGPR configs identical perf) -> the ~2000 extra cyc/step over the
// 768-cyc fdot2 issue floor is STRUCTURE: 2 barriers, the hh[768] LDS
// round-trip, a gate phase running on 4/16 waves, and IEEE-div sigmoids.
//
// New structure:
//  - Quad-group q (= wv*16 + lane>>2, q in [0,128)) owns hidden units
//    2q, 2q+1 and computes ALL THREE gate rows for them:
//    rows {2q, 2q+1} (r), {+256} (z), {+512} (n). After the quad DPP
//    butterfly every lane of the quad holds hr/hz/hn for both units ->
//    gates computed locally, in-register. No hh buffer, no gate phase.
//  - h kept as f16 pairs in a DOUBLE-BUFFERED LDS vector -> ONE barrier
//    per step (ping-pong: the end-of-step barrier orders writes of buf[nxt]
//    against next step's reads; writes of buf[nxt] cannot race step t-1's
//    reads of the same buffer because that barrier already passed).
//  - Sigmoid/tanh via exp2 with PRE-SCALED arguments: xp GEMM scales r,z
//    rows by log2e and n rows by 2*log2e; W_hh rows and bhn likewise at
//    load/convert time. Gate = v_rcp(1 + v_exp(-x)): 4 VALU ops, no v_div.
//
// hbuf layout (per buffer, 160 dwords): h (256 f16 = 128 dwords) in 4
// k-chunks of 32 dwords at stride 40 -> the 4 distinct per-quad b128
// addresses hit disjoint bank groups (verified 0 conflicts in r1-r3).
// Gate write: lane kc==0 of quad q writes units {2q,2q+1} as ONE dword at
// chunk q>>5, dword q&31 -> 16 consecutive dwords per wave, conflict-free.
__global__ __launch_bounds__(512) void gru_seq(
    const float* __restrict__ xp,      // [T, 768], pre-scaled by L2E/2L2E
    const float* __restrict__ Whh,     // [768, 256]
    const float* __restrict__ bhh,     // [768]
    const float* __restrict__ h0,      // [256] or nullptr (zeros)
    float* __restrict__ hs_out,        // [T, 256] or nullptr
    float* __restrict__ hT_out) {      // [256] or nullptr
  __shared__ __align__(16) uint hbufd[2][160];

  const int tid = threadIdx.x;
  const int lane = tid & 63;
  const int wv = tid >> 6;              // 0..7
  const int kc = lane & 3;              // k-chunk [64*kc, 64*kc+64)
  const int q = wv * 16 + (lane >> 2);  // 0..127; units 2q, 2q+1
  const int u0 = 2 * q;

  // wreg[uu*3+gg]: unit u0+uu, gate gg (0=r,1=z,2=n), pre-scaled.
  h2 wreg[6][32];
#pragma unroll
  for (int uu = 0; uu < 2; ++uu) {
#pragma unroll
    for (int gg = 0; gg < 3; ++gg) {
      const float sc = (gg == 2) ? (2.f * L2E) : L2E;
      const float* wr = Whh + (size_t)(u0 + uu + gg * HN) * HN + kc * 64;
#pragma unroll
      for (int p = 0; p < 32; ++p) {
        float2 f = *(const float2*)(wr + 2 * p);
        wreg[uu * 3 + gg][p] = h2{(_Float16)(f.x * sc), (_Float16)(f.y * sc)};
      }
    }
  }

  float hj0 = h0 ? h0[u0] : 0.f;
  float hj1 = h0 ? h0[u0 + 1] : 0.f;
  const float bhn0 = bhh[2 * HN + u0] * (2.f * L2E);
  const float bhn1 = bhh[2 * HN + u0 + 1] * (2.f * L2E);

  if (tid < 128) {
    float a = h0 ? h0[2 * tid] : 0.f;
    float b = h0 ? h0[2 * tid + 1] : 0.f;
    h2 pv = h2{(_Float16)a, (_Float16)b};
    hbufd[0][(tid >> 5) * 40 + (tid & 31)] = __builtin_bit_cast(uint, pv);
  }
  __syncthreads();

  const float* xpt = xp + u0;
  const int wadr = (q >> 5) * 40 + (q & 31);

  for (int t = 0; t < TT; ++t) {
    // This step's x-projection (3 float2 loads; land during the matvec).
    float2 xr = *(const float2*)(xpt);
    float2 xz = *(const float2*)(xpt + HN);
    float2 xn = *(const float2*)(xpt + 2 * HN);
    xpt += H3;

    // Matvec: 6 rows x 64 k per thread (f16 dot2, fp32 accumulate).
    const uint* hb = &hbufd[t & 1][kc * 40];
    float a[6] = {0.f, 0.f, 0.f, 0.f, 0.f, 0.f};
#pragma unroll
    for (int qq = 0; qq < 8; ++qq) {
      uint4 v = *(const uint4*)&hb[qq * 4];
      uint hwv[4] = {v.x, v.y, v.z, v.w};
#pragma unroll
      for (int i = 0; i < 6; ++i)
#pragma unroll
        for (int p = 0; p < 4; ++p)
          a[i] = fdot2(wreg[i][qq * 4 + p], __builtin_bit_cast(h2, hwv[p]), a[i]);
    }

    // Quad butterfly: all 4 lanes end with the full k-sum (bit-identical).
#pragma unroll
    for (int i = 0; i < 6; ++i) {
      float v = a[i];
      v += dpp_qperm<0xB1>(v);  // xor 1
      v += dpp_qperm<0x4E>(v);  // xor 2
      a[i] = v;
    }

    // Gates, fully local (args pre-scaled by log2e / 2log2e).
    float r0 = fast_rcp(1.f + fast_exp2(-(xr.x + a[0])));
    float z0 = fast_rcp(1.f + fast_exp2(-(xz.x + a[1])));
    float n0 = fmaf(2.f, fast_rcp(1.f + fast_exp2(-fmaf(r0, a[2] + bhn0, xn.x))), -1.f);
    hj0 = fmaf(z0, hj0 - n0, n0);
    float r1 = fast_rcp(1.f + fast_exp2(-(xr.y + a[3])));
    float z1 = fast_rcp(1.f + fast_exp2(-(xz.y + a[4])));
    float n1 = fmaf(2.f, fast_rcp(1.f + fast_exp2(-fmaf(r1, a[5] + bhn1, xn.y))), -1.f);
    hj1 = fmaf(z1, hj1 - n1, n1);

    h2 pv = h2{(_Float16)hj0, (_Float16)hj1};
    if (kc == 0) {
      hbufd[(t & 1) ^ 1][wadr] = __builtin_bit_cast(uint, pv);
      if (hs_out) *(float2*)&hs_out[(size_t)t * HN + u0] = make_float2(hj0, hj1);
    }
    __syncthreads();
  }
  if (hT_out && kc == 0) *(float2*)&hT_out[u0] = make_float2(hj0, hj1);
}

extern "C" void kernel_launch(void* const* d_in, const int* in_sizes, int n_in,
                              void* d_out, int out_size, void* d_ws, size_t ws_size,
                              hipStream_t stream) {
  const float* x     = (const float*)d_in[0];   // [1, 2048, 1739]
  const float* Wih_e = (const float*)d_in[2];   // [768, 1739]
  const float* Whh_e = (const float*)d_in[3];   // [768, 256]
  const float* bih_e = (const float*)d_in[4];   // [768]
  const float* bhh_e = (const float*)d_in[5];   // [768]
  const float* Wih_d = (const float*)d_in[6];
  const float* Whh_d = (const float*)d_in[7];
  const float* bih_d = (const float*)d_in[8];
  const float* bhh_d = (const float*)d_in[9];
  const float* Wout  = (const float*)d_in[10];  // [1739, 256]
  const float* bout  = (const float*)d_in[11];  // [1739]
  float* out = (float*)d_out;                   // [2048, 1, 1739]

  float* ws = (float*)d_ws;
  float* xpe  = ws;                              // 2048*768
  float* xpd  = xpe + (size_t)TT * H3;           // 2048*768
  float* hs   = xpd + (size_t)TT * H3;           // 2048*256
  float* henc = hs + (size_t)TT * HN;            // 256

  dim3 blk(256);
  // x-projections, pre-scaled for exp2-based gates:
  //   rows [0,512) (r,z): (x@W^T + bih + bhh) * log2e
  //   rows [512,768) (n): (x@W^T + bih) * 2log2e   (bhh n-part in-gate)
  gemm_abt<<<dim3(12, 32), blk, 0, stream>>>(x, TT, II, Wih_e, H3, bih_e, bhh_e, 2 * HN,
                                             L2E, 2.f * L2E, 2 * HN, xpe);
  gemm_abt<<<dim3(12, 32), blk, 0, stream>>>(x, TT, II, Wih_d, H3, bih_d, bhh_d, 2 * HN,
                                             L2E, 2.f * L2E, 2 * HN, xpd);
  // encoder scan -> henc
  gru_seq<<<1, 512, 0, stream>>>(xpe, Whh_e, bhh_e, nullptr, nullptr, henc);
  // decoder scan -> hs
  gru_seq<<<1, 512, 0, stream>>>(xpd, Whh_d, bhh_d, henc, hs, nullptr);
  // output projection (unscaled)
  gemm_abt<<<dim3(28, 32), blk, 0, stream>>>(hs, TT, HN, Wout, II, bout, nullptr, 0,
                                             1.f, 1.f, 0, out);
}